// Round 4
// baseline (201.071 us; speedup 1.0000x reference)
//
#include <hip/hip_runtime.h>

// TwoHotCategoricalLoss: loss = mean_rows( log(sum exp(x)) - sum_col w(col)*x[col] )
// w(col) = max(0, 1 - |col - u|), u = (t - MIN)/delta  (exact two-hot hat fn).
//
// Roofline-shaped config:
//   grid = nrows/64 = 2048 blocks, 256 thr, __launch_bounds__(256,8) (VGPR<=64)
//   -> 8 blocks/CU * 256 CU = 2048: EXACTLY one residency round, zero tail,
//      32 waves/CU. Block b owns contiguous rows [64b, 64b+64) (L2 locality).
//   Each wave: 16 rows as 8 batches of 2 rows (32 lanes/row, 2 float4/lane),
//   depth-2 register prefetch (one batch always in HBM flight per wave).

#define NCOLS 256

struct B2 {
    float4 a0, a1;   // this lane's two 16B chunks: cols [4h..4h+3], [128+4h..]
    float  t;        // target of this lane's row
};

__device__ __forceinline__ B2 load2(const float* __restrict__ logits,
                                    const float* __restrict__ target,
                                    int row, int h)
{
    B2 b;
    const float4* rp = reinterpret_cast<const float4*>(logits + (size_t)row * NCOLS);
    b.a0 = rp[h];
    b.a1 = rp[h + 32];
    b.t  = target[row];
    return b;
}

__device__ __forceinline__ float comp2(const B2& b, float c0)
{
    const float inv_delta = 255.0f / 40.0f;
    const float u = (b.t + 20.0f) * inv_delta;   // fractional bin index
    float s = 0.0f, d = 0.0f;
    const float v0[4] = {b.a0.x, b.a0.y, b.a0.z, b.a0.w};
    const float v1[4] = {b.a1.x, b.a1.y, b.a1.z, b.a1.w};
    #pragma unroll
    for (int k = 0; k < 4; ++k) {
        s += __expf(v0[k]);
        float w = fmaxf(1.0f - fabsf(c0 + (float)k - u), 0.0f);
        d = fmaf(w, v0[k], d);
        s += __expf(v1[k]);
        w = fmaxf(1.0f - fabsf(c0 + (float)(128 + k) - u), 0.0f);
        d = fmaf(w, v1[k], d);
    }
    // 5-step butterfly within each 32-lane row group
    #pragma unroll
    for (int o = 1; o < 32; o <<= 1) {
        s += __shfl_xor(s, o, 64);
        d += __shfl_xor(d, o, 64);
    }
    return __logf(s) - d;    // identical across the 32 lanes of the group
}

__global__ __launch_bounds__(256, 8) void twohot_ce_kernel(
    const float* __restrict__ logits, const float* __restrict__ target,
    float* __restrict__ out, int nrows)
{
    const int lane = threadIdx.x & 63;
    const int wid  = threadIdx.x >> 6;
    const int h    = lane & 31;     // lane within 32-lane row group
    const int half = lane >> 5;     // which row of the batch pair
    const float c0 = (float)(h << 2);

    // wave owns 16 contiguous rows; batch b handles rows wrow0+2b (+half)
    const int wrow0 = blockIdx.x * 64 + wid * 16 + half;

    float acc = 0.0f;

    B2 A  = load2(logits, target, wrow0 + 0, h);
    B2 Bb = load2(logits, target, wrow0 + 2, h);

    #pragma unroll 1
    for (int b = 0; b < 8; b += 2) {
        acc += comp2(A, c0);
        if (b + 2 < 8) A  = load2(logits, target, wrow0 + (b + 2) * 2, h);
        acc += comp2(Bb, c0);
        if (b + 3 < 8) Bb = load2(logits, target, wrow0 + (b + 3) * 2, h);
    }

    // halves hold disjoint row sums (even/odd rows of each pair): combine
    acc += __shfl_xor(acc, 32, 64);

    __shared__ float wave_acc[4];
    if (lane == 0) wave_acc[wid] = acc;
    __syncthreads();
    if (threadIdx.x == 0) {
        const float tot = wave_acc[0] + wave_acc[1] + wave_acc[2] + wave_acc[3];
        atomicAdd(out, tot / (float)nrows);
    }
}

// Cleanup for nrows not divisible by 64 (not hit at N=131072): one wave per row.
__global__ __launch_bounds__(64) void twohot_ce_tail(
    const float* __restrict__ logits, const float* __restrict__ target,
    float* __restrict__ out, int row0, int nrows)
{
    const int row = row0 + blockIdx.x;
    if (row >= nrows) return;
    const int lane = threadIdx.x;
    const float4 x = reinterpret_cast<const float4*>(logits + (size_t)row * NCOLS)[lane];
    const float inv_delta = 255.0f / 40.0f;
    const float u = (target[row] + 20.0f) * inv_delta;
    const float c0 = (float)(lane << 2);
    float s = 0.0f, d = 0.0f;
    const float v[4] = {x.x, x.y, x.z, x.w};
    #pragma unroll
    for (int k = 0; k < 4; ++k) {
        s += __expf(v[k]);
        const float w = fmaxf(1.0f - fabsf(c0 + (float)k - u), 0.0f);
        d = fmaf(w, v[k], d);
    }
    #pragma unroll
    for (int o = 1; o < 64; o <<= 1) {
        s += __shfl_xor(s, o, 64);
        d += __shfl_xor(d, o, 64);
    }
    if (lane == 0) atomicAdd(out, (__logf(s) - d) / (float)nrows);
}

extern "C" void kernel_launch(void* const* d_in, const int* in_sizes, int n_in,
                              void* d_out, int out_size, void* d_ws, size_t ws_size,
                              hipStream_t stream) {
    const float* logits = (const float*)d_in[0];
    const float* target = (const float*)d_in[1];
    float* out = (float*)d_out;
    const int nrows = in_sizes[1];      // N = 131072

    // d_out is poisoned to 0xAA before every timed launch; zero it first.
    hipMemsetAsync(out, 0, sizeof(float), stream);

    const int nblocks = nrows / 64;
    if (nblocks > 0)
        twohot_ce_kernel<<<dim3(nblocks), dim3(256), 0, stream>>>(
            logits, target, out, nrows);
    const int rem = nrows - nblocks * 64;
    if (rem > 0)
        twohot_ce_tail<<<dim3(rem), dim3(64), 0, stream>>>(
            logits, target, out, nblocks * 64, nrows);
}